// Round 11
// baseline (241.567 us; speedup 1.0000x reference)
//
#include <hip/hip_runtime.h>

// ---------------------------------------------------------------------------
// MultiheadSelfAttention: B=2, S=2048, D=1024, H=16, DK=64
// cast weights->bf16 ; fused QKV GEMM (x fp32 read + in-staging cvt, reg-
// prefetch ds_write staging, XOR swizzle, V transposed, Q scaled log2e/8) ;
// flash attention (key-split waves, no-max exp2 softmax, PV via K=16 MFMA
// from regs, XCD swizzle) ; output projection (glds staging, 128x64).
// ---------------------------------------------------------------------------

typedef __attribute__((ext_vector_type(8))) short bf16x8;   // 8 bf16
typedef __attribute__((ext_vector_type(4))) short bf16x4;   // 4 bf16
typedef __attribute__((ext_vector_type(4))) float f32x4;
typedef __attribute__((ext_vector_type(2))) unsigned int u32x2;

#define GK 1024
#define SEQ 2048
#define NHEAD 16
#define DKD 64
#define PADW 72      // padded LDS row stride (elems) for attn/epilogue tiles

#define MFMA32(a, b, c) __builtin_amdgcn_mfma_f32_16x16x32_bf16((a), (b), (c), 0, 0, 0)
#define MFMA16(a, b, c) __builtin_amdgcn_mfma_f32_16x16x16bf16_1k((a), (b), (c), 0, 0, 0)

#if __has_builtin(__builtin_amdgcn_exp2f)
#define EXP2(x) __builtin_amdgcn_exp2f(x)
#else
#define EXP2(x) exp2f(x)
#endif

// Q scale: (1/sqrt(64)) * log2(e), folded into the Q projection epilogue
#define QSCALE 0.18033688011f

static __device__ __forceinline__ unsigned short f2bf(float f) {
    unsigned int u = __float_as_uint(f);
    u += 0x7fffu + ((u >> 16) & 1u);     // RNE
    return (unsigned short)(u >> 16);
}

// pack two f32 -> two bf16 in one dword (a -> low half). round-half-up + v_perm.
static __device__ __forceinline__ unsigned int pack_bf2(float a, float b) {
    unsigned int ua = __float_as_uint(a) + 0x8000u;
    unsigned int ub = __float_as_uint(b) + 0x8000u;
    return __builtin_amdgcn_perm(ub, ua, 0x07060302u);  // [b.hi16, a.hi16]
}

// ---------------------------------------------------------------- weight casts
// 4096 blocks: 0..1023 Wq ; 1024..2047 Wk ; 2048..3071 Wv ; 3072..4095 Wo
__global__ __launch_bounds__(256) void cast_w(const float* __restrict__ wq,
                                              const float* __restrict__ wk,
                                              const float* __restrict__ wv,
                                              const float* __restrict__ wo,
                                              unsigned short* __restrict__ Wqkv,
                                              unsigned short* __restrict__ Wob) {
    const int bid = blockIdx.x;
    const float* src; unsigned short* dst; int off;
    if (bid < 1024)      { src = wq; dst = Wqkv;           off = bid; }
    else if (bid < 2048) { src = wk; dst = Wqkv + 1048576; off = bid - 1024; }
    else if (bid < 3072) { src = wv; dst = Wqkv + 2097152; off = bid - 2048; }
    else                 { src = wo; dst = Wob;            off = bid - 3072; }
    const int i = off * 1024 + threadIdx.x * 4;
    float4 v = *(const float4*)(src + i);
    u32x2 p; p.x = pack_bf2(v.x, v.y); p.y = pack_bf2(v.z, v.w);
    *(u32x2*)(dst + i) = p;
}

// ---------------------------------------------------------------- QKV GEMM
// C = x * Wqkv^T, M=4096(=B*S), N=3072, K=1024. A = x fp32 (cvt in staging),
// B = Wqkv bf16. Reg-prefetch staging: tile kt+1 global loads issue after the
// staging barrier into VGPRs (no vmcnt(0) drain at barriers); ds_write_b128
// into XOR-swizzled single-buffer LDS (chunk c' of row r holds col chunk
// c'^(r&7)). Epilogue = per-wave LDS scratch, unioned with As/Bs.
__global__ __launch_bounds__(256) void gemm_qkv(const float* __restrict__ X,
                                                const unsigned short* __restrict__ Bw,
                                                unsigned short* __restrict__ outb) {
    constexpr int LOOP_BYTES = 128 * 64 * 2 * 2;          // As + Bs
    constexpr int EPI_BYTES  = 4 * 64 * PADW * 2;
    constexpr int SMEM_BYTES = LOOP_BYTES > EPI_BYTES ? LOOP_BYTES : EPI_BYTES;
    __shared__ __align__(16) unsigned char SMEM[SMEM_BYTES];
    unsigned short* As = (unsigned short*)SMEM;            // [128][64] swizzled
    unsigned short* Bs = As + 128 * 64;                    // [128][64] swizzled

    const int t    = threadIdx.x;
    const int lane = t & 63;
    const int w    = t >> 6;
    const int wm   = (w >> 1) * 64;
    const int wn   = (w & 1) * 64;
    const int bm0  = blockIdx.x * 128;
    const int bn0  = blockIdx.y * 128;
    const int lm   = lane & 15;
    const int lq   = lane >> 4;
    const int swzb = lm & 7;

    // staging geometry: chunk q = i*256+t ; row r = i*32 + (t>>3) ;
    // global col-chunk gc = (t&7) ^ (r&7) = (t&7) ^ ((t>>3)&7)  (i-invariant)
    const int srow = t >> 3;
    const int gc   = (t & 7) ^ (srow & 7);
    const float*           Xa = X  + (size_t)(bm0 + srow) * GK + gc * 8;
    const unsigned short*  Bb = Bw + (size_t)(bn0 + srow) * GK + gc * 8;

    f32x4 acc[4][4];
    const f32x4 Z4 = {0.f, 0.f, 0.f, 0.f};
#pragma unroll
    for (int i = 0; i < 4; i++)
#pragma unroll
        for (int j = 0; j < 4; j++) acc[i][j] = Z4;

    uint4 pa[4], pb[4];
    // prefetch tile 0
#pragma unroll
    for (int i = 0; i < 4; ++i) {
        const float* xp = Xa + (size_t)i * 32 * GK;       // rows i*32
        float4 f0 = *(const float4*)(xp);
        float4 f1 = *(const float4*)(xp + 4);
        pa[i].x = pack_bf2(f0.x, f0.y); pa[i].y = pack_bf2(f0.z, f0.w);
        pa[i].z = pack_bf2(f1.x, f1.y); pa[i].w = pack_bf2(f1.z, f1.w);
        pb[i] = *(const uint4*)(Bb + (size_t)i * 32 * GK);
    }

    for (int kt = 0; kt < 16; ++kt) {
        __syncthreads();                       // previous frag reads retired
#pragma unroll
        for (int i = 0; i < 4; ++i) {
            *(uint4*)(As + (size_t)(i * 256 + t) * 8) = pa[i];
            *(uint4*)(Bs + (size_t)(i * 256 + t) * 8) = pb[i];
        }
        __syncthreads();                       // staging visible
        if (kt + 1 < 16) {
            const int k0 = (kt + 1) * 64;
#pragma unroll
            for (int i = 0; i < 4; ++i) {
                const float* xp = Xa + (size_t)i * 32 * GK + k0;
                float4 f0 = *(const float4*)(xp);
                float4 f1 = *(const float4*)(xp + 4);
                pa[i].x = pack_bf2(f0.x, f0.y); pa[i].y = pack_bf2(f0.z, f0.w);
                pa[i].z = pack_bf2(f1.x, f1.y); pa[i].w = pack_bf2(f1.z, f1.w);
                pb[i] = *(const uint4*)(Bb + (size_t)i * 32 * GK + k0);
            }
        }
#pragma unroll
        for (int kk = 0; kk < 2; ++kk) {
            const int swz = ((kk * 4 + lq) ^ swzb) * 8;
            bf16x8 af[4], bf[4];
#pragma unroll
            for (int i = 0; i < 4; i++)
                af[i] = *(const bf16x8*)(As + (wm + i * 16 + lm) * 64 + swz);
#pragma unroll
            for (int j = 0; j < 4; j++)
                bf[j] = *(const bf16x8*)(Bs + (wn + j * 16 + lm) * 64 + swz);
#pragma unroll
            for (int i = 0; i < 4; i++)
#pragma unroll
                for (int j = 0; j < 4; j++)
                    acc[i][j] = MFMA32(af[i], bf[j], acc[i][j]);
        }
    }

    __syncthreads();                           // K-loop LDS reads retired
    unsigned short* E  = (unsigned short*)SMEM;
    unsigned short* Ew = E + w * (64 * PADW);
    const int nbase = bn0 + wn;
    const int which = nbase >> 10;             // 0=Q 1=K 2=V (wave-uniform)
    const int hh    = (nbase & 1023) >> 6;
    if (which != 2) {
        const float sc = (which == 0) ? QSCALE : 1.0f;
#pragma unroll
        for (int i = 0; i < 4; i++)
#pragma unroll
            for (int j = 0; j < 4; j++)
#pragma unroll
                for (int r = 0; r < 4; r++)
                    Ew[(i * 16 + lq * 4 + r) * PADW + j * 16 + lm] =
                        f2bf(acc[i][j][r] * sc);
        unsigned short* dst = outb + (size_t)which * 4194304;
#pragma unroll
        for (int rep = 0; rep < 8; ++rep) {
            const int mm = rep * 8 + (lane >> 3);
            const int d0 = (lane & 7) * 8;
            uint4 v = *(const uint4*)(Ew + mm * PADW + d0);
            const int m_g = bm0 + wm + mm;
            const int b = m_g >> 11, s = m_g & 2047;
            *(uint4*)(dst + (((size_t)(b * NHEAD + hh)) * SEQ + s) * DKD + d0) = v;
        }
    } else {
#pragma unroll
        for (int i = 0; i < 4; i++)
#pragma unroll
            for (int j = 0; j < 4; j++) {
                u32x2 pk;
                pk.x = pack_bf2(acc[i][j][0], acc[i][j][1]);
                pk.y = pack_bf2(acc[i][j][2], acc[i][j][3]);
                *(u32x2*)(Ew + (j * 16 + lm) * PADW + i * 16 + lq * 4) = pk;
            }
        unsigned short* dst = outb + (size_t)2 * 4194304;
#pragma unroll
        for (int rep = 0; rep < 8; ++rep) {
            const int nn = rep * 8 + (lane >> 3);
            const int mc = (lane & 7) * 8;
            uint4 v = *(const uint4*)(Ew + nn * PADW + mc);
            const int m_g = bm0 + wm + mc;
            const int b = m_g >> 11, s0 = m_g & 2047;
            *(uint4*)(dst + (((size_t)(b * NHEAD + hh)) * DKD + nn) * SEQ + s0) = v;
        }
    }
}

// ---------------------------------------------------------------- output proj
// out[m][n] = Ob[m][:] . Wob[n][:] + bias[n]; 128x64 tiles, glds staging,
// BK=64 XOR swizzle. A: 1024 chunks (4/thread); B: 512 chunks (2/thread).
__global__ __launch_bounds__(256) void gemm_proj(const unsigned short* __restrict__ A,
                                                 const unsigned short* __restrict__ Bw,
                                                 float* __restrict__ outf,
                                                 const float* __restrict__ bias) {
    __shared__ __align__(16) unsigned short As[128 * 64];
    __shared__ __align__(16) unsigned short Bs[64 * 64];

    const int t    = threadIdx.x;
    const int lane = t & 63;
    const int w    = t >> 6;
    const int wm   = (w >> 1) * 64;
    const int wn   = (w & 1) * 32;
    const int bm0  = blockIdx.x * 128;
    const int bn0  = blockIdx.y * 64;
    const int lm   = lane & 15;
    const int lq   = lane >> 4;
    const int swzb = lm & 7;

    const unsigned short* Ab = A + (size_t)bm0 * GK;
    const unsigned short* Bb = Bw + (size_t)bn0 * GK;

    f32x4 acc[4][2];
    const f32x4 Z4 = {0.f, 0.f, 0.f, 0.f};
#pragma unroll
    for (int i = 0; i < 4; i++)
#pragma unroll
        for (int j = 0; j < 2; j++) acc[i][j] = Z4;

    const int q_uni = (t & ~63);

    for (int k0 = 0; k0 < GK; k0 += 64) {
        __syncthreads();
#pragma unroll
        for (int i = 0; i < 4; ++i) {
            int q   = i * 256 + t;
            int r   = q >> 3;
            int gcs = (q & 7) ^ (r & 7);
            int q0  = i * 256 + q_uni;
            __builtin_amdgcn_global_load_lds(
                (const __attribute__((address_space(1))) void*)(Ab + (size_t)r * GK + k0 + gcs * 8),
                (__attribute__((address_space(3))) void*)(As + (size_t)q0 * 8),
                16, 0, 0);
        }
#pragma unroll
        for (int i = 0; i < 2; ++i) {          // B: 64 rows x 8 chunks = 512 chunks
            int q   = i * 256 + t;
            int r   = q >> 3;
            int gcs = (q & 7) ^ (r & 7);
            int q0  = i * 256 + q_uni;
            __builtin_amdgcn_global_load_lds(
                (const __attribute__((address_space(1))) void*)(Bb + (size_t)r * GK + k0 + gcs * 8),
                (__attribute__((address_space(3))) void*)(Bs + (size_t)q0 * 8),
                16, 0, 0);
        }
        __syncthreads();

#pragma unroll
        for (int kk = 0; kk < 2; ++kk) {
            const int swz = ((kk * 4 + lq) ^ swzb) * 8;
            bf16x8 af[4], bf[2];
#pragma unroll
            for (int i = 0; i < 4; i++)
                af[i] = *(const bf16x8*)(As + (wm + i * 16 + lm) * 64 + swz);
#pragma unroll
            for (int j = 0; j < 2; j++)
                bf[j] = *(const bf16x8*)(Bs + (wn + j * 16 + lm) * 64 + swz);
#pragma unroll
            for (int i = 0; i < 4; i++)
#pragma unroll
                for (int j = 0; j < 2; j++)
                    acc[i][j] = MFMA32(af[i], bf[j], acc[i][j]);
        }
    }

#pragma unroll
    for (int i = 0; i < 4; i++) {
        const int mbase = bm0 + wm + i * 16 + lq * 4;
#pragma unroll
        for (int j = 0; j < 2; j++) {
            const int n = bn0 + wn + j * 16 + lm;
#pragma unroll
            for (int r = 0; r < 4; r++)
                outf[(size_t)(mbase + r) * 1024 + n] = acc[i][j][r] + bias[n];
        }
    }
}

// ---------------------------------------------------------------- flash attention
// KEY-SPLIT (round-7 structure, unchanged).
__global__ __launch_bounds__(256, 3) void attn_kernel(const unsigned short* __restrict__ Qg,
                                                      const unsigned short* __restrict__ Kg,
                                                      const unsigned short* __restrict__ Vtg,
                                                      unsigned short* __restrict__ Og) {
    __shared__ __align__(16) unsigned short KV[2][2][64 * PADW];  // 36,864 B

    const int id  = blockIdx.x;
    const int xcd = id & 7;
    const int j8  = id >> 3;
    const int bh  = xcd * 4 + (j8 & 3);
    const int qb  = j8 >> 2;
    const unsigned short* Qp  = Qg  + ((size_t)bh * SEQ + qb * 64) * DKD;
    const unsigned short* Kp  = Kg  + (size_t)bh * SEQ * DKD;
    const unsigned short* Vtp = Vtg + (size_t)bh * DKD * SEQ;

    const int t    = threadIdx.x;
    const int lane = t & 63;
    const int w    = t >> 6;
    const int lm   = lane & 15;
    const int kq   = lane >> 4;

    const f32x4 Z4 = {0.f, 0.f, 0.f, 0.f};

    bf16x8 aq[4][2];
#pragma unroll
    for (int c = 0; c < 4; ++c)
#pragma unroll
        for (int kk = 0; kk < 2; ++kk)
            aq[c][kk] = *(const bf16x8*)(Qp + (size_t)(c * 16 + lm) * DKD + kk * 32 + kq * 8);

    f32x4 o[4][4];
    float ls[4];
#pragma unroll
    for (int c = 0; c < 4; ++c) {
        ls[c] = 0.f;
#pragma unroll
        for (int dj = 0; dj < 4; ++dj) o[c][dj] = Z4;
    }

    const int sr = t >> 2, sc = (t & 3) * 16;
    uint4 kreg0, kreg1, vreg0, vreg1;
    {
        const unsigned short* kp = Kp + (size_t)sr * DKD + sc;
        const unsigned short* vp = Vtp + (size_t)sr * SEQ + sc;
        uint4 a0 = *(const uint4*)(kp), a1 = *(const uint4*)(kp + 8);
        uint4 b0 = *(const uint4*)(vp), b1 = *(const uint4*)(vp + 8);
        uint4* dk = (uint4*)(&KV[0][0][sr * PADW + sc]); dk[0] = a0; dk[1] = a1;
        uint4* dv = (uint4*)(&KV[0][1][sr * PADW + sc]); dv[0] = b0; dv[1] = b1;
    }
    {
        const unsigned short* kp = Kp + (size_t)(64 + sr) * DKD + sc;
        kreg0 = *(const uint4*)(kp); kreg1 = *(const uint4*)(kp + 8);
        const unsigned short* vp = Vtp + (size_t)sr * SEQ + 64 + sc;
        vreg0 = *(const uint4*)(vp); vreg1 = *(const uint4*)(vp + 8);
    }

    for (int kt = 0; kt < 32; ++kt) {
        __syncthreads();
        if (kt + 1 < 32) {
            uint4* dk = (uint4*)(&KV[(kt + 1) & 1][0][sr * PADW + sc]);
            dk[0] = kreg0; dk[1] = kreg1;
            uint4* dv = (uint4*)(&KV[(kt + 1) & 1][1][sr * PADW + sc]);
            dv[0] = vreg0; dv[1] = vreg1;
        }
        if (kt + 2 < 32) {
            const unsigned short* kp = Kp + (size_t)((kt + 2) * 64 + sr) * DKD + sc;
            kreg0 = *(const uint4*)(kp); kreg1 = *(const uint4*)(kp + 8);
            const unsigned short* vp = Vtp + (size_t)sr * SEQ + (kt + 2) * 64 + sc;
            vreg0 = *(const uint4*)(vp); vreg1 = *(const uint4*)(vp + 8);
        }
        const unsigned short* Kc = &KV[kt & 1][0][0];
        const unsigned short* Vc = &KV[kt & 1][1][0];

        bf16x8 ak0 = *(const bf16x8*)(Kc + (w * 16 + lm) * PADW + kq * 8);
        bf16x8 ak1 = *(const bf16x8*)(Kc + (w * 16 + lm) * PADW + 32 + kq * 8);
        f32x4 s[4];
#pragma unroll
        for (int c = 0; c < 4; ++c) {
            s[c] = MFMA32(ak0, aq[c][0], Z4);
            s[c] = MFMA32(ak1, aq[c][1], s[c]);
        }

#pragma unroll
        for (int c = 0; c < 4; ++c) {
#pragma unroll
            for (int r = 0; r < 4; ++r) s[c][r] = EXP2(s[c][r]);
            ls[c] += (s[c][0] + s[c][1]) + (s[c][2] + s[c][3]);
        }

        bf16x4 ap[4];
#pragma unroll
        for (int c = 0; c < 4; ++c) {
            u32x2 pk;
            pk.x = pack_bf2(s[c][0], s[c][1]);
            pk.y = pack_bf2(s[c][2], s[c][3]);
            ap[c] = __builtin_bit_cast(bf16x4, pk);
        }

#pragma unroll
        for (int dj = 0; dj < 4; ++dj) {
            bf16x4 bv = *(const bf16x4*)(Vc + (dj * 16 + lm) * PADW + w * 16 + kq * 4);
#pragma unroll
            for (int c = 0; c < 4; ++c)
                o[c][dj] = MFMA16(ap[c], bv, o[c][dj]);
        }
    }

    __syncthreads();
    float* Lf = (float*)(&KV[0][0][0]);

#pragma unroll
    for (int c = 0; c < 4; ++c) {
        float v = ls[c];
        v += __shfl_xor(v, 16);
        v += __shfl_xor(v, 32);
        if (kq == 0) Lf[w * 64 + c * 16 + lm] = v;
    }
    __syncthreads();

    const int rq = t >> 2;
    const int dq = (t & 3) * 8;
    float li = (Lf[rq] + Lf[64 + rq]) + (Lf[128 + rq] + Lf[192 + rq]);
#if __has_builtin(__builtin_amdgcn_rcpf)
    li = __builtin_amdgcn_rcpf(li);
#else
    li = 1.0f / li;
#endif
    __syncthreads();

    const int b = bh >> 4, h = bh & 15;
#pragma unroll
    for (int p = 0; p < 2; ++p) {
#pragma unroll
        for (int c = 0; c < 4; ++c)
#pragma unroll
            for (int djh = 0; djh < 2; ++djh) {
                const int dj = 2 * p + djh;
#pragma unroll
                for (int r = 0; r < 4; ++r)
                    Lf[(w * 64 + c * 16 + kq * 4 + r) * 36 + djh * 16 + lm] = o[c][dj][r];
            }
        __syncthreads();
        f32x4 a0 = Z4, a1 = Z4;
#pragma unroll
        for (int wp = 0; wp < 4; ++wp) {
            a0 += *(const f32x4*)(Lf + (wp * 64 + rq) * 36 + dq);
            a1 += *(const f32x4*)(Lf + (wp * 64 + rq) * 36 + dq + 4);
        }
        uint4 outv;
        outv.x = pack_bf2(a0[0] * li, a0[1] * li);
        outv.y = pack_bf2(a0[2] * li, a0[3] * li);
        outv.z = pack_bf2(a1[0] * li, a1[1] * li);
        outv.w = pack_bf2(a1[2] * li, a1[3] * li);
        *(uint4*)(Og + (((size_t)(b * SEQ + qb * 64 + rq)) * NHEAD + h) * DKD + p * 32 + dq) = outv;
        __syncthreads();
    }
}

// ---------------------------------------------------------------- launcher
extern "C" void kernel_launch(void* const* d_in, const int* in_sizes, int n_in,
                              void* d_out, int out_size, void* d_ws, size_t ws_size,
                              hipStream_t stream) {
    const float* x  = (const float*)d_in[0];
    const float* Wq = (const float*)d_in[1];
    const float* Wk = (const float*)d_in[2];
    const float* Wv = (const float*)d_in[3];
    const float* Wo = (const float*)d_in[4];
    const float* bo = (const float*)d_in[5];
    float* out = (float*)d_out;

    unsigned short* ws = (unsigned short*)d_ws;
    unsigned short* Wqkv = ws + 4194304;             // [3072][1024] (Wq|Wk|Wv)
    unsigned short* Wob  = ws + 7340032;             // [1024][1024]
    unsigned short* QKV  = ws + 8388608;             // Q,K:[b,h,s,d]; V:[b,h,d,s]
    unsigned short* Ob   = ws + 20971520;            // [4096][1024] = [b,s,h,d]

    cast_w<<<4096, 256, 0, stream>>>(Wq, Wk, Wv, Wo, Wqkv, Wob);
    gemm_qkv<<<dim3(32, 24), 256, 0, stream>>>(x, Wqkv, QKV);
    attn_kernel<<<1024, 256, 0, stream>>>(QKV, QKV + 4194304, QKV + 8388608, Ob);
    gemm_proj<<<dim3(32, 16), 256, 0, stream>>>(Ob, Wob, out, bo);
}